// Round 5
// baseline (3412.101 us; speedup 1.0000x reference)
//
#include <hip/hip_runtime.h>
#include <hip/hip_bf16.h>
#include <math.h>

#define B_SZ 4
#define CDIM 512
#define NPIX 4096
#define EPSN 1e-5f

typedef unsigned short u16;

// bf16 (bits) -> f32: exact
static __device__ __forceinline__ float bf2f(u16 u) {
    return __uint_as_float(((unsigned)u) << 16);
}
// f32 -> bf16 bits, round-to-nearest-even
static __device__ __forceinline__ u16 f2bf(float f) {
    unsigned u = __float_as_uint(f);
    unsigned r = (u + 0x7FFFu + ((u >> 16) & 1u)) >> 16;
    return (u16)r;
}

// ---------------------------------------------------------------------------
// conv1x1 (one batch): Y[o,n] = bf16( bias[o] + sum_c W[o,c] * X[c,n] )
// fp32 inputs, bf16 output. [512,512] x [512,4096]; 64x64 tile, TK=16.
// ---------------------------------------------------------------------------
__global__ __launch_bounds__(256) void conv_gemm_b(const float* __restrict__ X,
    const float* __restrict__ W, const float* __restrict__ bias, u16* __restrict__ Y)
{
    const int tx = threadIdx.x, ty = threadIdx.y;
    const int t  = ty * 16 + tx;
    const int n0 = blockIdx.x * 64;
    const int o0 = blockIdx.y * 64;

    __shared__ float Wt[16][65];   // [c][o]
    __shared__ float Xt[16][64];   // [c][n]

    float acc[4][4] = {};
    const int wo = t >> 2, wc = (t & 3) * 4;   // W tile loader: 64 o x 16 c
    const int xk = t >> 4, xn = (t & 15) * 4;  // X tile loader: 16 c x 64 n

    for (int c0 = 0; c0 < CDIM; c0 += 16) {
        float4 w = *(const float4*)&W[(size_t)(o0 + wo) * CDIM + c0 + wc];
        float4 x = *(const float4*)&X[(size_t)(c0 + xk) * NPIX + n0 + xn];
        __syncthreads();
        Wt[wc+0][wo] = w.x; Wt[wc+1][wo] = w.y; Wt[wc+2][wo] = w.z; Wt[wc+3][wo] = w.w;
        *(float4*)&Xt[xk][xn] = x;
        __syncthreads();
        #pragma unroll
        for (int kk = 0; kk < 16; kk++) {
            float a[4], bb[4];
            #pragma unroll
            for (int i = 0; i < 4; i++) a[i]  = Wt[kk][ty*4+i];
            #pragma unroll
            for (int j = 0; j < 4; j++) bb[j] = Xt[kk][tx*4+j];
            #pragma unroll
            for (int i = 0; i < 4; i++)
                #pragma unroll
                for (int j = 0; j < 4; j++)
                    acc[i][j] += a[i] * bb[j];
        }
    }
    #pragma unroll
    for (int i = 0; i < 4; i++) {
        float bs = bias[o0 + ty*4 + i];
        ushort4 r;
        r.x = f2bf(acc[i][0] + bs);
        r.y = f2bf(acc[i][1] + bs);
        r.z = f2bf(acc[i][2] + bs);
        r.w = f2bf(acc[i][3] + bs);
        *(ushort4*)&Y[(size_t)(o0 + ty*4 + i) * NPIX + n0 + tx*4] = r;
    }
}

// ---------------------------------------------------------------------------
// col_norm (one batch, bf16 in): norm[n] = sqrt(sum_c F[c,n]^2)
// ---------------------------------------------------------------------------
__global__ __launch_bounds__(256) void col_norm_b(const u16* __restrict__ F, float* __restrict__ norm)
{
    const int n = blockIdx.x * 256 + threadIdx.x;
    float s = 0.f;
    for (int c = 0; c < CDIM; c++) {
        float v = bf2f(F[(size_t)c * NPIX + n]);
        s += v * v;
    }
    norm[n] = sqrtf(s);
}

// ---------------------------------------------------------------------------
// s_gemm strip (bf16 in/out): S[nl,m] = relu( dot/((Fn[n]+e)(Gn[m]+e)) + 1 )
// rows n = strip_base + nl
// ---------------------------------------------------------------------------
__global__ __launch_bounds__(256) void s_gemm_b(const u16* __restrict__ F, const u16* __restrict__ G,
    const float* __restrict__ Fn, const float* __restrict__ Gn, u16* __restrict__ S, int strip_base)
{
    const int tx = threadIdx.x, ty = threadIdx.y;
    const int t  = ty * 16 + tx;
    const int m0 = blockIdx.x * 64;
    const int nl0 = blockIdx.y * 64;           // local row-tile
    const int n0 = strip_base + nl0;           // global col index into F

    __shared__ float Ft[16][64];   // [c][n]
    __shared__ float Gt[16][64];   // [c][m]

    float acc[4][4] = {};
    const int xk = t >> 4, xn = (t & 15) * 4;

    for (int c0 = 0; c0 < CDIM; c0 += 16) {
        ushort4 f = *(const ushort4*)&F[(size_t)(c0 + xk) * NPIX + n0 + xn];
        ushort4 g = *(const ushort4*)&G[(size_t)(c0 + xk) * NPIX + m0 + xn];
        __syncthreads();
        Ft[xk][xn+0] = bf2f(f.x); Ft[xk][xn+1] = bf2f(f.y);
        Ft[xk][xn+2] = bf2f(f.z); Ft[xk][xn+3] = bf2f(f.w);
        Gt[xk][xn+0] = bf2f(g.x); Gt[xk][xn+1] = bf2f(g.y);
        Gt[xk][xn+2] = bf2f(g.z); Gt[xk][xn+3] = bf2f(g.w);
        __syncthreads();
        #pragma unroll
        for (int kk = 0; kk < 16; kk++) {
            float a[4], bb[4];
            #pragma unroll
            for (int i = 0; i < 4; i++) a[i]  = Ft[kk][ty*4+i];
            #pragma unroll
            for (int j = 0; j < 4; j++) bb[j] = Gt[kk][tx*4+j];
            #pragma unroll
            for (int i = 0; i < 4; i++)
                #pragma unroll
                for (int j = 0; j < 4; j++)
                    acc[i][j] += a[i] * bb[j];
        }
    }
    float fi[4], gi[4];
    #pragma unroll
    for (int i = 0; i < 4; i++) fi[i] = 1.f / (Fn[n0 + ty*4 + i] + EPSN);
    #pragma unroll
    for (int j = 0; j < 4; j++) gi[j] = 1.f / (Gn[m0 + tx*4 + j] + EPSN);
    #pragma unroll
    for (int i = 0; i < 4; i++) {
        ushort4 r;
        r.x = f2bf(fmaxf(acc[i][0]*fi[i]*gi[0] + 1.f, 0.f));
        r.y = f2bf(fmaxf(acc[i][1]*fi[i]*gi[1] + 1.f, 0.f));
        r.z = f2bf(fmaxf(acc[i][2]*fi[i]*gi[2] + 1.f, 0.f));
        r.w = f2bf(fmaxf(acc[i][3]*fi[i]*gi[3] + 1.f, 0.f));
        *(ushort4*)&S[(size_t)(nl0 + ty*4 + i) * NPIX + m0 + tx*4] = r;
    }
}

// ---------------------------------------------------------------------------
// row_sum strip (bf16 in): rs[strip_base + nl] = sum_m S[nl,m]
// ---------------------------------------------------------------------------
__global__ __launch_bounds__(256) void row_sum_b(const u16* __restrict__ S, float* __restrict__ rs,
    int strip_base)
{
    const int nl = blockIdx.x;
    const int tid = threadIdx.x;
    const u16* row = S + (size_t)nl * NPIX;
    float s = 0.f;
    for (int m = tid * 4; m < NPIX; m += 256 * 4) {
        ushort4 v = *(const ushort4*)&row[m];
        s += bf2f(v.x) + bf2f(v.y) + bf2f(v.z) + bf2f(v.w);
    }
    __shared__ float red[256];
    red[tid] = s; __syncthreads();
    for (int st = 128; st; st >>= 1) {
        if (tid < st) red[tid] += red[tid + st];
        __syncthreads();
    }
    if (tid == 0) rs[strip_base + nl] = red[0];
}

// ---------------------------------------------------------------------------
// pv_fused strip (one batch): for c-tile x n-tile
//   mean = (sum_m S[n,m]*H[c,m])/(rs[n]+eps), msq = (sum_m S*H^2)/(rs+eps)
//   out[c,n] = fp32( sqrt(relu(msq-mean^2)) * (content[c,n]-mu[c])*isd[c] + mean )
// content fp32, OUT fp32.
// ---------------------------------------------------------------------------
__global__ __launch_bounds__(256) void pv_fused(const u16* __restrict__ S, const u16* __restrict__ H,
    const float* __restrict__ rs, const float* __restrict__ content_b,
    const float* __restrict__ mu, const float* __restrict__ isd,
    float* __restrict__ out_b, int strip_base)
{
    const int tx = threadIdx.x, ty = threadIdx.y;
    const int t  = ty * 16 + tx;
    const int nl0 = blockIdx.x * 64;
    const int c0  = blockIdx.y * 64;

    __shared__ float Ht[64][17];   // [c][m]
    __shared__ float St[64][17];   // [n][m]

    float accm[4][4] = {};
    float accs[4][4] = {};
    const int lr = t >> 2, lm = (t & 3) * 4;   // loader: 64 rows x 16 m

    for (int m0 = 0; m0 < NPIX; m0 += 16) {
        ushort4 h = *(const ushort4*)&H[(size_t)(c0 + lr) * NPIX + m0 + lm];
        ushort4 s = *(const ushort4*)&S[(size_t)(nl0 + lr) * NPIX + m0 + lm];
        __syncthreads();
        Ht[lr][lm+0]=bf2f(h.x); Ht[lr][lm+1]=bf2f(h.y); Ht[lr][lm+2]=bf2f(h.z); Ht[lr][lm+3]=bf2f(h.w);
        St[lr][lm+0]=bf2f(s.x); St[lr][lm+1]=bf2f(s.y); St[lr][lm+2]=bf2f(s.z); St[lr][lm+3]=bf2f(s.w);
        __syncthreads();
        #pragma unroll
        for (int kk = 0; kk < 16; kk++) {
            float a[4], bb[4];
            #pragma unroll
            for (int i = 0; i < 4; i++) a[i] = Ht[ty*4+i][kk];
            #pragma unroll
            for (int j = 0; j < 4; j++) bb[j] = St[tx*4+j][kk];
            #pragma unroll
            for (int i = 0; i < 4; i++)
                #pragma unroll
                for (int j = 0; j < 4; j++) {
                    accm[i][j] += a[i] * bb[j];
                    accs[i][j] += (a[i] * a[i]) * bb[j];
                }
        }
    }
    float inv[4];
    #pragma unroll
    for (int j = 0; j < 4; j++) inv[j] = 1.f / (rs[strip_base + nl0 + tx*4 + j] + EPSN);
    #pragma unroll
    for (int i = 0; i < 4; i++) {
        const int cg = c0 + ty*4 + i;
        const size_t ro = (size_t)cg * NPIX + strip_base + nl0 + tx*4;
        float4 cv = *(const float4*)&content_b[ro];
        const float mc = mu[cg], ic = isd[cg];
        float cn[4] = { (cv.x-mc)*ic, (cv.y-mc)*ic, (cv.z-mc)*ic, (cv.w-mc)*ic };
        float4 r;
        float* rp = (float*)&r;
        #pragma unroll
        for (int j = 0; j < 4; j++) {
            float mean = accm[i][j] * inv[j];
            float msq  = accs[i][j] * inv[j];
            float sd   = sqrtf(fmaxf(msq - mean*mean, 0.f));
            rp[j] = sd * cn[j] + mean;
        }
        *(float4*)&out_b[ro] = r;
    }
}

// ---------------------------------------------------------------------------
// content_stats: per (b,c) mean and 1/std (unbiased var, +1e-5), fp32 input
// ---------------------------------------------------------------------------
__global__ __launch_bounds__(256) void content_stats(const float* __restrict__ x,
    float* __restrict__ mu, float* __restrict__ isd)
{
    const int bc = blockIdx.x;
    const int tid = threadIdx.x;
    const float* row = x + (size_t)bc * NPIX;
    float s = 0.f, s2 = 0.f;
    for (int i = tid * 4; i < NPIX; i += 256 * 4) {
        float4 v = *(const float4*)&row[i];
        s  += v.x + v.y + v.z + v.w;
        s2 += v.x*v.x + v.y*v.y + v.z*v.z + v.w*v.w;
    }
    __shared__ float r1[256], r2[256];
    r1[tid] = s; r2[tid] = s2; __syncthreads();
    for (int st = 128; st; st >>= 1) {
        if (tid < st) { r1[tid] += r1[tid+st]; r2[tid] += r2[tid+st]; }
        __syncthreads();
    }
    if (tid == 0) {
        float m = r1[0] / NPIX;
        float var = (r2[0] - (float)NPIX * m * m) / (float)(NPIX - 1);
        mu[bc]  = m;
        isd[bc] = rsqrtf(var + 1e-5f);
    }
}

// ---------------------------------------------------------------------------
extern "C" void kernel_launch(void* const* d_in, const int* in_sizes, int n_in,
                              void* d_out, int out_size, void* d_ws, size_t ws_size,
                              hipStream_t stream)
{
    // fp32 inputs, fp32 output (per reference dtypes).
    const float* content     = (const float*)d_in[0];
    const float* style       = (const float*)d_in[1];
    const float* content_key = (const float*)d_in[2];
    const float* style_key   = (const float*)d_in[3];
    const float* Wf  = (const float*)d_in[4];
    const float* bf_ = (const float*)d_in[5];
    const float* Wg  = (const float*)d_in[6];
    const float* bg  = (const float*)d_in[7];
    const float* Wh  = (const float*)d_in[8];
    const float* bh  = (const float*)d_in[9];
    float* out = (float*)d_out;

    const size_t TB = (size_t)CDIM * NPIX;      // 2,097,152 elems per batch-tensor

    // pick largest S-strip that fits ws_size (bf16 internals keep this small):
    const size_t tail_f = 3 * (size_t)NPIX + 2 * (size_t)B_SZ * CDIM;
    const size_t fixed  = 3 * TB * 2 + tail_f * 4 + 1024;
    int ns = 256;
    for (int cand = NPIX; cand >= 256; cand >>= 1) {
        if (fixed + (size_t)NPIX * cand * 2 <= ws_size) { ns = cand; break; }
    }

    u16* Fb = (u16*)d_ws;                        // TB bf16
    u16* Gb = Fb + TB;                           // TB bf16
    u16* Hb = Gb + TB;                           // TB bf16
    u16* Sb = Hb + TB;                           // NPIX*ns bf16
    float* Fn  = (float*)(Sb + (size_t)NPIX * ns);
    float* Gn  = Fn + NPIX;
    float* rsb = Gn + NPIX;
    float* mu  = rsb + NPIX;
    float* isd = mu + (size_t)B_SZ * CDIM;

    dim3 blk(16, 16);
    content_stats<<<B_SZ * CDIM, 256, 0, stream>>>(content, mu, isd);

    for (int b = 0; b < B_SZ; b++) {
        const size_t bo = (size_t)b * TB;
        conv_gemm_b<<<dim3(NPIX/64, CDIM/64), blk, 0, stream>>>(content_key + bo, Wf, bf_, Fb);
        conv_gemm_b<<<dim3(NPIX/64, CDIM/64), blk, 0, stream>>>(style_key   + bo, Wg, bg,  Gb);
        conv_gemm_b<<<dim3(NPIX/64, CDIM/64), blk, 0, stream>>>(style       + bo, Wh, bh,  Hb);
        col_norm_b<<<NPIX/256, 256, 0, stream>>>(Fb, Fn);
        col_norm_b<<<NPIX/256, 256, 0, stream>>>(Gb, Gn);

        for (int s0 = 0; s0 < NPIX; s0 += ns) {
            s_gemm_b<<<dim3(NPIX/64, ns/64), blk, 0, stream>>>(Fb, Gb, Fn, Gn, Sb, s0);
            row_sum_b<<<ns, 256, 0, stream>>>(Sb, rsb, s0);
            pv_fused<<<dim3(ns/64, CDIM/64), blk, 0, stream>>>(Sb, Hb, rsb,
                    content + bo, mu + b*CDIM, isd + b*CDIM, out + bo, s0);
        }
    }
}

// Round 6
// 703.054 us; speedup vs baseline: 4.8533x; 4.8533x over previous
//
#include <hip/hip_runtime.h>
#include <hip/hip_bf16.h>
#include <math.h>

#define B_SZ 4
#define CDIM 512
#define NPIX 4096
#define EPSN 1e-5f

typedef unsigned short u16;
typedef __attribute__((ext_vector_type(8))) short bf16x8;
typedef __attribute__((ext_vector_type(4))) float f32x4;

#define MFMA_BF16 __builtin_amdgcn_mfma_f32_16x16x32_bf16

static __device__ __forceinline__ float bf2f(u16 u) {
    return __uint_as_float(((unsigned)u) << 16);
}
static __device__ __forceinline__ u16 f2bf(float f) {
    unsigned u = __float_as_uint(f);
    unsigned r = (u + 0x7FFFu + ((u >> 16) & 1u)) >> 16;
    return (u16)r;
}

// ---------------------------------------------------------------------------
// transpose_f2b: X fp32 [CDIM][NPIX] -> XT bf16 [NPIX][CDIM]. 64x64 tiles.
// ---------------------------------------------------------------------------
__global__ __launch_bounds__(256) void transpose_f2b(const float* __restrict__ X,
    u16* __restrict__ XT)
{
    __shared__ float T[64][65];
    const int t = threadIdx.x;
    const int n0 = blockIdx.x * 64, c0 = blockIdx.y * 64;
    #pragma unroll
    for (int p = 0; p < 4; p++) {
        int c_l = (t >> 4) + p * 16;
        int n_l = (t & 15) * 4;
        float4 v = *(const float4*)&X[(size_t)(c0 + c_l) * NPIX + n0 + n_l];
        T[c_l][n_l+0] = v.x; T[c_l][n_l+1] = v.y; T[c_l][n_l+2] = v.z; T[c_l][n_l+3] = v.w;
    }
    __syncthreads();
    #pragma unroll
    for (int p = 0; p < 4; p++) {
        int n_l = t >> 2;
        int cs  = (t & 3) * 4 + p * 16;
        ushort4 r;
        r.x = f2bf(T[cs+0][n_l]); r.y = f2bf(T[cs+1][n_l]);
        r.z = f2bf(T[cs+2][n_l]); r.w = f2bf(T[cs+3][n_l]);
        *(ushort4*)&XT[(size_t)(n0 + n_l) * CDIM + c0 + cs] = r;
    }
}

// ---------------------------------------------------------------------------
// conv64<TMODE>: D[o][n] = sum_c W[o][c] * XT[n][c]  (MFMA 16x16x32 bf16)
// 64x64 tile, 4 waves (2x2 of 32x32). TMODE: store D^T into Y=[n][o] (bf16).
// else: Y[o][n] = bf16(v), Y2[o][n] = bf16(v^2)   (v includes bias).
// ---------------------------------------------------------------------------
template<bool TMODE>
__global__ __launch_bounds__(256) void conv64(const u16* __restrict__ XT,
    const float* __restrict__ W, const float* __restrict__ bias,
    u16* __restrict__ Y, u16* __restrict__ Y2)
{
    const int t = threadIdx.x;
    const int lane = t & 63, wv = t >> 6;
    const int wr = wv >> 1, wc = wv & 1;
    const int n0 = blockIdx.x * 64;
    const int o0 = blockIdx.y * 64;
    const int g = lane >> 4, li = lane & 15;

    __shared__ short Aw[64][40];
    __shared__ short Bx[64][40];

    f32x4 acc[2][2] = {};
    const int srow = t >> 2, sseg = (t & 3) * 8;

    for (int kb = 0; kb < CDIM; kb += 32) {
        float4 w0 = *(const float4*)&W[(size_t)(o0 + srow) * CDIM + kb + sseg];
        float4 w1 = *(const float4*)&W[(size_t)(o0 + srow) * CDIM + kb + sseg + 4];
        bf16x8 bv = *(const bf16x8*)&XT[(size_t)(n0 + srow) * CDIM + kb + sseg];
        bf16x8 wa;
        wa[0] = (short)f2bf(w0.x); wa[1] = (short)f2bf(w0.y);
        wa[2] = (short)f2bf(w0.z); wa[3] = (short)f2bf(w0.w);
        wa[4] = (short)f2bf(w1.x); wa[5] = (short)f2bf(w1.y);
        wa[6] = (short)f2bf(w1.z); wa[7] = (short)f2bf(w1.w);
        __syncthreads();
        *(bf16x8*)&Aw[srow][sseg] = wa;
        *(bf16x8*)&Bx[srow][sseg] = bv;
        __syncthreads();
        bf16x8 a[2], b[2];
        #pragma unroll
        for (int i = 0; i < 2; i++) a[i] = *(const bf16x8*)&Aw[wr*32 + i*16 + li][g*8];
        #pragma unroll
        for (int j = 0; j < 2; j++) b[j] = *(const bf16x8*)&Bx[wc*32 + j*16 + li][g*8];
        #pragma unroll
        for (int i = 0; i < 2; i++)
            #pragma unroll
            for (int j = 0; j < 2; j++)
                acc[i][j] = MFMA_BF16(a[i], b[j], acc[i][j], 0, 0, 0);
    }

    #pragma unroll
    for (int i = 0; i < 2; i++) {
        const int orow = o0 + wr*32 + i*16 + 4*g;   // 4 consecutive o via regs
        float4 bs = *(const float4*)&bias[orow];
        #pragma unroll
        for (int j = 0; j < 2; j++) {
            const int ncol = n0 + wc*32 + j*16 + li;
            if (TMODE) {
                ushort4 r;
                r.x = f2bf(acc[i][j][0] + bs.x);
                r.y = f2bf(acc[i][j][1] + bs.y);
                r.z = f2bf(acc[i][j][2] + bs.z);
                r.w = f2bf(acc[i][j][3] + bs.w);
                *(ushort4*)&Y[(size_t)ncol * CDIM + orow] = r;
            } else {
                const float bb[4] = { bs.x, bs.y, bs.z, bs.w };
                #pragma unroll
                for (int r = 0; r < 4; r++) {
                    float v = acc[i][j][r] + bb[r];
                    u16 hv = f2bf(v);
                    float hf = bf2f(hv);
                    Y [(size_t)(orow + r) * NPIX + ncol] = hv;
                    Y2[(size_t)(orow + r) * NPIX + ncol] = f2bf(hf * hf);
                }
            }
        }
    }
}

// ---------------------------------------------------------------------------
// col_norm_rows: FT [NPIX][CDIM] bf16 -> norm[n] = sqrt(sum_c FT[n][c]^2)
// ---------------------------------------------------------------------------
__global__ __launch_bounds__(256) void col_norm_rows(const u16* __restrict__ FT,
    float* __restrict__ norm)
{
    const int n = blockIdx.x * 256 + threadIdx.x;
    const u16* row = FT + (size_t)n * CDIM;
    float s = 0.f;
    for (int c = 0; c < CDIM; c += 8) {
        bf16x8 v = *(const bf16x8*)&row[c];
        #pragma unroll
        for (int e = 0; e < 8; e++) { float f = bf2f((u16)v[e]); s += f * f; }
    }
    norm[n] = sqrtf(s);
}

// ---------------------------------------------------------------------------
// s_gemm128: S[nl][m] = bf16(relu(dot(F_n,G_m)/((Fn+e)(Gn+e)) + 1))
// A = FT rows (strip-global n), B = GT rows (m); K = CDIM. 128x128 tile,
// 4 waves (2x2 of 64x64), MFMA 16x16x32.
// ---------------------------------------------------------------------------
__global__ __launch_bounds__(256) void s_gemm128(const u16* __restrict__ FT,
    const u16* __restrict__ GT, const float* __restrict__ Fn, const float* __restrict__ Gn,
    u16* __restrict__ S, int strip_base)
{
    const int t = threadIdx.x;
    const int lane = t & 63, wv = t >> 6;
    const int wr = wv >> 1, wc = wv & 1;
    const int m0  = blockIdx.x * 128;
    const int nl0 = blockIdx.y * 128;
    const int ng0 = strip_base + nl0;
    const int g = lane >> 4, li = lane & 15;

    __shared__ short As[128][40];
    __shared__ short Bs[128][40];

    f32x4 acc[4][4] = {};
    const int srow = t >> 2, sseg = (t & 3) * 8;

    for (int kb = 0; kb < CDIM; kb += 32) {
        bf16x8 fa0 = *(const bf16x8*)&FT[(size_t)(ng0 + srow     ) * CDIM + kb + sseg];
        bf16x8 fa1 = *(const bf16x8*)&FT[(size_t)(ng0 + srow + 64) * CDIM + kb + sseg];
        bf16x8 gb0 = *(const bf16x8*)&GT[(size_t)(m0  + srow     ) * CDIM + kb + sseg];
        bf16x8 gb1 = *(const bf16x8*)&GT[(size_t)(m0  + srow + 64) * CDIM + kb + sseg];
        __syncthreads();
        *(bf16x8*)&As[srow     ][sseg] = fa0;
        *(bf16x8*)&As[srow + 64][sseg] = fa1;
        *(bf16x8*)&Bs[srow     ][sseg] = gb0;
        *(bf16x8*)&Bs[srow + 64][sseg] = gb1;
        __syncthreads();
        bf16x8 a[4], b[4];
        #pragma unroll
        for (int i = 0; i < 4; i++) a[i] = *(const bf16x8*)&As[wr*64 + i*16 + li][g*8];
        #pragma unroll
        for (int j = 0; j < 4; j++) b[j] = *(const bf16x8*)&Bs[wc*64 + j*16 + li][g*8];
        #pragma unroll
        for (int i = 0; i < 4; i++)
            #pragma unroll
            for (int j = 0; j < 4; j++)
                acc[i][j] = MFMA_BF16(a[i], b[j], acc[i][j], 0, 0, 0);
    }

    float gi[4];
    #pragma unroll
    for (int j = 0; j < 4; j++) gi[j] = 1.f / (Gn[m0 + wc*64 + j*16 + li] + EPSN);
    #pragma unroll
    for (int i = 0; i < 4; i++) {
        const int nl = nl0 + wr*64 + i*16 + 4*g;
        float4 fn4 = *(const float4*)&Fn[strip_base + nl];
        const float fi4[4] = { 1.f/(fn4.x + EPSN), 1.f/(fn4.y + EPSN),
                               1.f/(fn4.z + EPSN), 1.f/(fn4.w + EPSN) };
        #pragma unroll
        for (int j = 0; j < 4; j++) {
            const int m = m0 + wc*64 + j*16 + li;
            #pragma unroll
            for (int r = 0; r < 4; r++) {
                float v = fmaxf(acc[i][j][r] * fi4[r] * gi[j] + 1.f, 0.f);
                S[(size_t)(nl + r) * NPIX + m] = f2bf(v);
            }
        }
    }
}

// ---------------------------------------------------------------------------
// row_sum strip (bf16 in): rs[strip_base + nl] = sum_m S[nl,m]
// ---------------------------------------------------------------------------
__global__ __launch_bounds__(256) void row_sum_b(const u16* __restrict__ S,
    float* __restrict__ rs, int strip_base)
{
    const int nl = blockIdx.x;
    const int tid = threadIdx.x;
    const u16* row = S + (size_t)nl * NPIX;
    float s = 0.f;
    for (int m = tid * 8; m < NPIX; m += 256 * 8) {
        bf16x8 v = *(const bf16x8*)&row[m];
        #pragma unroll
        for (int e = 0; e < 8; e++) s += bf2f((u16)v[e]);
    }
    __shared__ float red[256];
    red[tid] = s; __syncthreads();
    for (int st = 128; st; st >>= 1) {
        if (tid < st) red[tid] += red[tid + st];
        __syncthreads();
    }
    if (tid == 0) rs[strip_base + nl] = red[0];
}

// ---------------------------------------------------------------------------
// pv64: mean/msq over k=m (MFMA, dual accumulators), fused AdaIN epilogue.
// D[c][n]: A=Hb rows c, A2=H2b rows c, B=Sb rows (strip-local n). K=NPIX.
// 64x64 tile, 4 waves (2x2 of 32x32). out fp32.
// ---------------------------------------------------------------------------
__global__ __launch_bounds__(256) void pv64(const u16* __restrict__ Hb,
    const u16* __restrict__ H2b, const u16* __restrict__ Sb, const float* __restrict__ rs,
    const float* __restrict__ content_b, const float* __restrict__ mu,
    const float* __restrict__ isd, float* __restrict__ out_b, int strip_base)
{
    const int t = threadIdx.x;
    const int lane = t & 63, wv = t >> 6;
    const int wr = wv >> 1, wc = wv & 1;
    const int nl0 = blockIdx.x * 64;
    const int c0  = blockIdx.y * 64;
    const int g = lane >> 4, li = lane & 15;

    __shared__ short Ah[64][40];
    __shared__ short A2h[64][40];
    __shared__ short Bss[64][40];

    f32x4 am[2][2] = {};
    f32x4 aq[2][2] = {};
    const int srow = t >> 2, sseg = (t & 3) * 8;

    for (int kb = 0; kb < NPIX; kb += 32) {
        bf16x8 ha  = *(const bf16x8*)&Hb [(size_t)(c0  + srow) * NPIX + kb + sseg];
        bf16x8 h2a = *(const bf16x8*)&H2b[(size_t)(c0  + srow) * NPIX + kb + sseg];
        bf16x8 sa  = *(const bf16x8*)&Sb [(size_t)(nl0 + srow) * NPIX + kb + sseg];
        __syncthreads();
        *(bf16x8*)&Ah [srow][sseg] = ha;
        *(bf16x8*)&A2h[srow][sseg] = h2a;
        *(bf16x8*)&Bss[srow][sseg] = sa;
        __syncthreads();
        bf16x8 a[2], a2[2], b[2];
        #pragma unroll
        for (int i = 0; i < 2; i++) {
            a[i]  = *(const bf16x8*)&Ah [wr*32 + i*16 + li][g*8];
            a2[i] = *(const bf16x8*)&A2h[wr*32 + i*16 + li][g*8];
        }
        #pragma unroll
        for (int j = 0; j < 2; j++) b[j] = *(const bf16x8*)&Bss[wc*32 + j*16 + li][g*8];
        #pragma unroll
        for (int i = 0; i < 2; i++)
            #pragma unroll
            for (int j = 0; j < 2; j++) {
                am[i][j] = MFMA_BF16(a[i],  b[j], am[i][j], 0, 0, 0);
                aq[i][j] = MFMA_BF16(a2[i], b[j], aq[i][j], 0, 0, 0);
            }
    }

    float inv[2];
    #pragma unroll
    for (int j = 0; j < 2; j++)
        inv[j] = 1.f / (rs[strip_base + nl0 + wc*32 + j*16 + li] + EPSN);
    #pragma unroll
    for (int i = 0; i < 2; i++) {
        const int c = c0 + wr*32 + i*16 + 4*g;
        float4 mu4 = *(const float4*)&mu[c];
        float4 is4 = *(const float4*)&isd[c];
        const float muA[4] = { mu4.x, mu4.y, mu4.z, mu4.w };
        const float isA[4] = { is4.x, is4.y, is4.z, is4.w };
        #pragma unroll
        for (int j = 0; j < 2; j++) {
            const int n = strip_base + nl0 + wc*32 + j*16 + li;
            #pragma unroll
            for (int r = 0; r < 4; r++) {
                float mean = am[i][j][r] * inv[j];
                float msq  = aq[i][j][r] * inv[j];
                float sd   = sqrtf(fmaxf(msq - mean * mean, 0.f));
                float cv   = content_b[(size_t)(c + r) * NPIX + n];
                out_b[(size_t)(c + r) * NPIX + n] = sd * (cv - muA[r]) * isA[r] + mean;
            }
        }
    }
}

// ---------------------------------------------------------------------------
// content_stats: per (b,c) mean and 1/std (unbiased var, +1e-5), fp32 input
// ---------------------------------------------------------------------------
__global__ __launch_bounds__(256) void content_stats(const float* __restrict__ x,
    float* __restrict__ mu, float* __restrict__ isd)
{
    const int bc = blockIdx.x;
    const int tid = threadIdx.x;
    const float* row = x + (size_t)bc * NPIX;
    float s = 0.f, s2 = 0.f;
    for (int i = tid * 4; i < NPIX; i += 256 * 4) {
        float4 v = *(const float4*)&row[i];
        s  += v.x + v.y + v.z + v.w;
        s2 += v.x*v.x + v.y*v.y + v.z*v.z + v.w*v.w;
    }
    __shared__ float r1[256], r2[256];
    r1[tid] = s; r2[tid] = s2; __syncthreads();
    for (int st = 128; st; st >>= 1) {
        if (tid < st) { r1[tid] += r1[tid+st]; r2[tid] += r2[tid+st]; }
        __syncthreads();
    }
    if (tid == 0) {
        float m = r1[0] / NPIX;
        float var = (r2[0] - (float)NPIX * m * m) / (float)(NPIX - 1);
        mu[bc]  = m;
        isd[bc] = rsqrtf(var + 1e-5f);
    }
}

// ---------------------------------------------------------------------------
extern "C" void kernel_launch(void* const* d_in, const int* in_sizes, int n_in,
                              void* d_out, int out_size, void* d_ws, size_t ws_size,
                              hipStream_t stream)
{
    const float* content     = (const float*)d_in[0];
    const float* style       = (const float*)d_in[1];
    const float* content_key = (const float*)d_in[2];
    const float* style_key   = (const float*)d_in[3];
    const float* Wf  = (const float*)d_in[4];
    const float* bf_ = (const float*)d_in[5];
    const float* Wg  = (const float*)d_in[6];
    const float* bg  = (const float*)d_in[7];
    const float* Wh  = (const float*)d_in[8];
    const float* bh  = (const float*)d_in[9];
    float* out = (float*)d_out;

    const size_t TB = (size_t)CDIM * NPIX;   // elems per batch-tensor

    // ws: FT, GT, Hb, H2b (bf16, TB each) + Sb (bf16, NPIX*ns) + fp32 tail
    const size_t tail_bytes = ((size_t)NPIX * 3 + 2 * (size_t)B_SZ * CDIM) * 4 + 256;
    const size_t fixed = 4 * TB * 2 + tail_bytes;
    int ns = 512;   // min 512 so Sb (>=4MB) can host the XT transpose scratch
    for (int cand = NPIX; cand >= 512; cand >>= 1) {
        if (fixed + (size_t)NPIX * cand * 2 <= ws_size) { ns = cand; break; }
    }

    u16* FT  = (u16*)d_ws;                   // [NPIX][CDIM]
    u16* GT  = FT + TB;                      // [NPIX][CDIM]
    u16* Hb  = GT + TB;                      // [CDIM][NPIX]
    u16* H2b = Hb + TB;                      // [CDIM][NPIX]
    u16* Sb  = H2b + TB;                     // [ns][NPIX]
    u16* XT  = Sb;                           // transpose scratch (before S strips)
    float* Fn  = (float*)(Sb + (size_t)NPIX * ns);
    float* Gn  = Fn + NPIX;
    float* rsb = Gn + NPIX;
    float* mu  = rsb + NPIX;
    float* isd = mu + (size_t)B_SZ * CDIM;

    content_stats<<<B_SZ * CDIM, 256, 0, stream>>>(content, mu, isd);

    const dim3 gT(NPIX/64, CDIM/64);     // transpose: 64x8
    const dim3 gC(NPIX/64, CDIM/64);     // conv: 64x8

    for (int b = 0; b < B_SZ; b++) {
        const size_t bo = (size_t)b * TB;

        transpose_f2b<<<gT, 256, 0, stream>>>(content_key + bo, XT);
        conv64<true><<<gC, 256, 0, stream>>>(XT, Wf, bf_, FT, nullptr);

        transpose_f2b<<<gT, 256, 0, stream>>>(style_key + bo, XT);
        conv64<true><<<gC, 256, 0, stream>>>(XT, Wg, bg, GT, nullptr);

        transpose_f2b<<<gT, 256, 0, stream>>>(style + bo, XT);
        conv64<false><<<gC, 256, 0, stream>>>(XT, Wh, bh, Hb, H2b);

        col_norm_rows<<<NPIX/256, 256, 0, stream>>>(FT, Fn);
        col_norm_rows<<<NPIX/256, 256, 0, stream>>>(GT, Gn);

        for (int s0 = 0; s0 < NPIX; s0 += ns) {
            s_gemm128<<<dim3(NPIX/128, ns/128), 256, 0, stream>>>(FT, GT, Fn, Gn, Sb, s0);
            row_sum_b<<<ns, 256, 0, stream>>>(Sb, rsb, s0);
            pv64<<<dim3(ns/64, CDIM/64), 256, 0, stream>>>(Sb ? Hb : Hb, H2b, Sb, rsb,
                    content + bo, mu + b*CDIM, isd + b*CDIM, out + bo, s0);
        }
    }
}